// Round 9
// baseline (354.627 us; speedup 1.0000x reference)
//
#include <hip/hip_runtime.h>
#include <cstdint>
#include <cmath>

// Binarized MLP via MX-fp4 scale-MFMA: 16384x1024 -> 2048 -> 2048 -> 2048 -> 2.
// R13 = R12 resubmit (Round-8 container failure diagnosed as infra flake;
// kernel audit found no divergent barriers, no OOB, no novel sync).
// R12 = R11 (256x128 tile, 8 waves 4m x 2n, wave 64x64, plain-sync loop,
// 2 blocks/CU) with A DE-STAGED: A fragments load directly from global
// (L2-resident, no swizzle needed, no barrier coupling) via 2-deep
// ping-pong register groups; only B goes through LDS (double-buffered
// 2 x 16KB, XOR-(row&7) pre-swizzled source, R11's verified zero-conflict
// read pattern). One __syncthreads per K-tile; its vmcnt drain covers only
// the 2 B-stage ld16s. Staged-DMA bytes/layer23: 393 -> 134 MB.
// fp4 e2m1 (+1=0x2, -1=0xA), mfma_scale_f32_16x16x128_f8f6f4, scales=1.0.

typedef int i32x4 __attribute__((ext_vector_type(4)));
typedef int i32x8 __attribute__((ext_vector_type(8)));
typedef float f32x4 __attribute__((ext_vector_type(4)));

static constexpr int Bsz = 16384;
static constexpr int Din = 1024;
static constexpr int Hid = 2048;

__device__ __forceinline__ void ld16(const void* g, void* l) {
  __builtin_amdgcn_global_load_lds(
      (const __attribute__((address_space(1))) void*)g,
      (__attribute__((address_space(3))) void*)l, 16, 0, 0);
}

// ---------------- fused prep: sign-quantize to packed fp4 + BN folds -------
// Each thread packs 8 floats -> 8 fp4 nibbles (u32). Elem j -> bits[4j+3:4j].
// blocks [0,8192): x (thr 0.5)   [8192,9216): w1   [9216,11264): w2
// [11264,13312): w3              [13312,13336): bnprep
__global__ void prep_kernel(
    const float* __restrict__ x, const float* __restrict__ w1,
    const float* __restrict__ w2, const float* __restrict__ w3,
    const float* __restrict__ g1, const float* __restrict__ b1,
    const float* __restrict__ m1, const float* __restrict__ v1,
    const float* __restrict__ g2, const float* __restrict__ b2,
    const float* __restrict__ m2, const float* __restrict__ v2,
    const float* __restrict__ g3, const float* __restrict__ b3,
    const float* __restrict__ m3, const float* __restrict__ v3,
    unsigned* __restrict__ A0, unsigned* __restrict__ W1s,
    unsigned* __restrict__ W2s, unsigned* __restrict__ W3s,
    float* __restrict__ a1, float* __restrict__ be1,
    float* __restrict__ a2, float* __restrict__ be2,
    float* __restrict__ a3, float* __restrict__ be3) {
  constexpr int BX = 8192, BW1 = 1024, BW2 = 2048, BW3 = 2048;
  const int blk = blockIdx.x;
  if (blk < BX + BW1 + BW2 + BW3) {
    const float* s;
    unsigned* d;
    float thr = 0.0f;
    int rb;
    if (blk < BX) {
      s = x; d = A0; thr = 0.5f; rb = 0;
    } else if (blk < BX + BW1) {
      s = w1; d = W1s; rb = BX;
    } else if (blk < BX + BW1 + BW2) {
      s = w2; d = W2s; rb = BX + BW1;
    } else {
      s = w3; d = W3s; rb = BX + BW1 + BW2;
    }
    int i = (blk - rb) * 256 + threadIdx.x;
    float4 v0 = ((const float4*)s)[2 * i];
    float4 v1 = ((const float4*)s)[2 * i + 1];
    float e[8] = {v0.x, v0.y, v0.z, v0.w, v1.x, v1.y, v1.z, v1.w};
    unsigned w = 0;
#pragma unroll
    for (int j = 0; j < 8; ++j)
      w |= ((e[j] >= thr) ? 0x2u : 0xAu) << (4 * j);
    d[i] = w;
  } else {
    int t = (blk - (BX + BW1 + BW2 + BW3)) * 256 + threadIdx.x;  // 0..6143
    int l = t >> 11, e = t & 2047;
    const float *g, *b, *m, *v;
    float *al, *be;
    if (l == 0) { g = g1; b = b1; m = m1; v = v1; al = a1; be = be1; }
    else if (l == 1) { g = g2; b = b2; m = m2; v = v2; al = a2; be = be2; }
    else { g = g3; b = b3; m = m3; v = v3; al = a3; be = be3; }
    float a = g[e] / sqrtf(v[e] + 1e-5f);
    al[e] = a;
    be[e] = b[e] - m[e] * a;
  }
}

// ---------------- fp4 MFMA layer: C = A x W^T -----------------------------
// Block 256(m) x 128(n) x K-tile 128B (=256 elems). 8 waves as 4(m) x 2(n);
// wave tile 64x64 = 4x4 mfma 16x16 frags.
// B: LDS double-buffer 2 x 16KB (128 rows x 128B), 16B chunks XOR-(row&7)
// swizzled at the global source; read pattern = R11's verified 0-conflict.
// A: direct global->VGPR dwordx4 per fragment (row-major, no swizzle);
// lane lr reads row m0+wm*64+mt*16+lr, bytes s*64 + lk*16 (+t*128).
// Per K-tile: 2 B-stage ld16 (next tile) + 8 A loads + 8 B ds_reads +
// 32 MFMA + one __syncthreads.
// FINAL: dot with sign(wout) rows, atomicAdd exact-integer partials (f32).
template <int K, bool FINAL>
__global__ __launch_bounds__(512, 4) void layer_mfma(
    const char* __restrict__ A, const char* __restrict__ W,
    const float* __restrict__ alpha, const float* __restrict__ beta,
    char* __restrict__ O, const float* __restrict__ wout,
    float* __restrict__ out) {
  constexpr int N = Hid;
  constexpr int KB = K / 2;    // bytes per packed row
  constexpr int NT = KB / 128; // K-tiles of 128B (=256 elems)
  __shared__ __align__(16) char lds[32768];  // B dbuf: 2 x 16KB

  const int tid = threadIdx.x;
  const int wave = tid >> 6, lane = tid & 63;

  // R11 swizzle: XCD x (= id&7) owns mp [x*8, x*8+8), np outermost.
  const int id = blockIdx.x;
  const int mp = (id & 7) * 8 + ((id >> 3) & 7);
  const int np = id >> 6;
  const int m0 = mp * 256, n0 = np * 128;

  // ---- B staging: 1024 chunks of 16B per tile; thread covers c=tid and
  // c=tid+512 (row +64, same kc). Linear LDS dest, pre-swizzled source.
  const int srow = tid >> 3;
  const int skc = (tid & 7) ^ (srow & 7);
  const char* gw0 = W + (size_t)(n0 + srow) * KB + skc * 16;
  const char* gw1 = gw0 + (size_t)64 * KB;
  const int l0 = tid * 16;

  // ---- fragment addressing ----
  const int lr = lane & 15, lk = lane >> 4;
  const int wm = wave >> 1, wn = wave & 1;
  const int xs0 = ((0 + lk) ^ (lr & 7)) * 16;  // B k-slice 0 chunk slot
  const int xs1 = ((4 + lk) ^ (lr & 7)) * 16;  // B k-slice 1 chunk slot
  const int bbase = (wn * 64 + lr) * 128;      // + rb + nt*2048 + xs
  // A: per-mt 32-bit voffsets from uniform base A+m0*KB; +64 for s=1 (imm),
  // += 128 per tile.
  const char* Ab = A + (size_t)m0 * KB;
  int voff[4];
#pragma unroll
  for (int mt = 0; mt < 4; ++mt)
    voff[mt] = (wm * 64 + mt * 16 + lr) * KB + lk * 16;

  f32x4 acc[4][4] = {};
  i32x8 a8[2] = {};    // fp4 uses low 4 regs; ping-pong 2-deep
  i32x8 b8[4] = {};

  // prologue: stage B tile 0 into buf0 (drain via __syncthreads).
  ld16(gw0, lds + l0);
  ld16(gw1, lds + l0 + 8192);
  gw0 += 128;
  gw1 += 128;
  __syncthreads();

#pragma unroll 1
  for (int t = 0; t < NT; ++t) {
    const int rb = (t & 1) << 14;   // read buffer
    const int wb = rb ^ 16384;      // write (prefetch) buffer
    if (t + 1 < NT) {
      ld16(gw0, lds + wb + l0);
      ld16(gw1, lds + wb + l0 + 8192);
      gw0 += 128;
      gw1 += 128;
    }
    // first A group (s=0, mt=0)
    *(i32x4*)&a8[0] = *(const i32x4*)(Ab + voff[0]);
#pragma unroll
    for (int s = 0; s < 2; ++s) {
      const int xs = s ? xs1 : xs0;
#pragma unroll
      for (int nt = 0; nt < 4; ++nt)
        *(i32x4*)&b8[nt] = *(const i32x4*)(lds + rb + bbase + nt * 2048 + xs);
#pragma unroll
      for (int mt = 0; mt < 4; ++mt) {
        // prefetch next A group (ping-pong distance 2 -> hazard-free)
        if (mt < 3)
          *(i32x4*)&a8[(mt + 1) & 1] =
              *(const i32x4*)(Ab + voff[mt + 1] + s * 64);
        else if (s == 0)
          *(i32x4*)&a8[0] = *(const i32x4*)(Ab + voff[0] + 64);
#pragma unroll
        for (int nt = 0; nt < 4; ++nt)
          acc[mt][nt] = __builtin_amdgcn_mfma_scale_f32_16x16x128_f8f6f4(
              a8[mt & 1], b8[nt], acc[mt][nt], 4, 4,  // FMT A=fp4, B=fp4
              0, 0x7F7F7F7F, 0, 0x7F7F7F7F);          // scales = 1.0
      }
    }
#pragma unroll
    for (int mt = 0; mt < 4; ++mt) voff[mt] += 128;
    __syncthreads();  // publishes wb; drains the 2 B-stage ld16s
  }

  float al[4], be[4];
#pragma unroll
  for (int nt = 0; nt < 4; ++nt) {
    int n = n0 + wn * 64 + nt * 16 + lr;
    al[nt] = alpha[n];
    be[nt] = beta[n];
  }

  if (!FINAL) {
    // pack output fp4 nibbles: lane pairs share one byte; even lane stores.
    const int bb0 = (n0 + wn * 64) >> 1;
#pragma unroll
    for (int mt = 0; mt < 4; ++mt)
#pragma unroll
      for (int r = 0; r < 4; ++r) {
        int m = m0 + wm * 64 + mt * 16 + lk * 4 + r;  // C/D row=(lane>>4)*4+reg
        char* orow = O + (size_t)m * (N / 2);
#pragma unroll
        for (int nt = 0; nt < 4; ++nt) {
          unsigned nib =
              (fmaf(al[nt], acc[mt][nt][r], be[nt]) >= 0.0f) ? 0x2u : 0xAu;
          unsigned pn = __shfl_xor(nib, 1, 64);
          if ((lane & 1) == 0)
            orow[bb0 + ((nt * 16 + lr) >> 1)] = (char)(nib | (pn << 4));
        }
      }
  } else {
    int ws0[4], ws1[4];
#pragma unroll
    for (int nt = 0; nt < 4; ++nt) {
      int n = n0 + wn * 64 + nt * 16 + lr;
      ws0[nt] = (wout[n] >= 0.0f) ? 1 : -1;
      ws1[nt] = (wout[2048 + n] >= 0.0f) ? 1 : -1;
    }
#pragma unroll
    for (int mt = 0; mt < 4; ++mt)
#pragma unroll
      for (int r = 0; r < 4; ++r) {
        int m = m0 + wm * 64 + mt * 16 + lk * 4 + r;
        int p0 = 0, p1 = 0;
#pragma unroll
        for (int nt = 0; nt < 4; ++nt) {
          int a = (fmaf(al[nt], acc[mt][nt][r], be[nt]) >= 0.0f) ? 1 : -1;
          p0 += a * ws0[nt];
          p1 += a * ws1[nt];
        }
        // reduce across lr (lane bits 0..3)
#pragma unroll
        for (int off = 1; off <= 8; off <<= 1) {
          p0 += __shfl_xor(p0, off, 64);
          p1 += __shfl_xor(p1, off, 64);
        }
        if (lr == 0) {
          atomicAdd(&out[m * 2 + 0], (float)p0);
          atomicAdd(&out[m * 2 + 1], (float)p1);
        }
      }
  }
}

extern "C" void kernel_launch(void* const* d_in, const int* in_sizes, int n_in,
                              void* d_out, int out_size, void* d_ws, size_t ws_size,
                              hipStream_t stream) {
  const float* x    = (const float*)d_in[0];
  const float* w1   = (const float*)d_in[1];
  const float* g1   = (const float*)d_in[2];
  const float* b1   = (const float*)d_in[3];
  const float* m1   = (const float*)d_in[4];
  const float* v1   = (const float*)d_in[5];
  const float* w2   = (const float*)d_in[6];
  const float* g2   = (const float*)d_in[7];
  const float* b2   = (const float*)d_in[8];
  const float* m2   = (const float*)d_in[9];
  const float* v2   = (const float*)d_in[10];
  const float* w3   = (const float*)d_in[11];
  const float* g3   = (const float*)d_in[12];
  const float* b3   = (const float*)d_in[13];
  const float* m3   = (const float*)d_in[14];
  const float* v3   = (const float*)d_in[15];
  const float* wout = (const float*)d_in[16];
  float* out = (float*)d_out;

  char* base = (char*)d_ws;
  size_t off = 0;
  auto take = [&](size_t bytes) -> char* {
    char* p = base + off;
    off += (bytes + 255) & ~(size_t)255;
    return p;
  };
  char* A0  = take((size_t)Bsz * Din / 2);
  char* Aa  = take((size_t)Bsz * Hid / 2);
  char* Ab  = take((size_t)Bsz * Hid / 2);
  char* W1s = take((size_t)Hid * Din / 2);
  char* W2s = take((size_t)Hid * Hid / 2);
  char* W3s = take((size_t)Hid * Hid / 2);
  float* a1  = (float*)take(Hid * 4);
  float* be1 = (float*)take(Hid * 4);
  float* a2  = (float*)take(Hid * 4);
  float* be2 = (float*)take(Hid * 4);
  float* a3  = (float*)take(Hid * 4);
  float* be3 = (float*)take(Hid * 4);

  hipMemsetAsync(d_out, 0, (size_t)out_size * sizeof(float), stream);

  prep_kernel<<<13336, 256, 0, stream>>>(
      x, w1, w2, w3,
      g1, b1, m1, v1, g2, b2, m2, v2, g3, b3, m3, v3,
      (unsigned*)A0, (unsigned*)W1s, (unsigned*)W2s, (unsigned*)W3s,
      a1, be1, a2, be2, a3, be3);

  // grid 1024: (16384/256) m-panels x (2048/128) n-panels, XCD-swizzled
  layer_mfma<Din, false><<<1024, 512, 0, stream>>>(A0, W1s, a1, be1, Aa,
                                                   nullptr, nullptr);
  layer_mfma<Hid, false><<<1024, 512, 0, stream>>>(Aa, W2s, a2, be2, Ab,
                                                   nullptr, nullptr);
  layer_mfma<Hid, true><<<1024, 512, 0, stream>>>(Ab, W3s, a3, be3, nullptr,
                                                  wout, out);
}

// Round 10
// 261.539 us; speedup vs baseline: 1.3559x; 1.3559x over previous
//
#include <hip/hip_runtime.h>
#include <cstdint>
#include <cmath>

// Binarized MLP via MX-fp4 scale-MFMA: 16384x1024 -> 2048 -> 2048 -> 2048 -> 2.
// R14 = R11 (best verified: 256x128 tile, 8 waves 4m x 2n, wave 64x64,
// 2 blocks/CU co-resident, XOR-(row&7) pre-swizzled staging, zero-conflict
// reads, fp4 e2m1 via mfma_scale_f32_16x16x128_f8f6f4 scales=1.0) with the
// A-stage taken OFF the per-tile critical path:
//   LDS = A dbuf 2x32KB @0/@32768 + B single 16KB @65536 = 80KB
//         (2 blocks/CU = 163840 B = exactly the LDS pool).
//   A(t+1) issues DURING tile t into the alternate A-buffer (full tile to
//   land); B(t) issues at tile start; per-wave vmcnt(4) before the
//   post-stage barrier drains {A(t),B(t)} and leaves A(t+1) in flight.
//   Exposed staging per tile: 48KB -> 16KB.
// Hazard audit: B overwrite guarded by lgkmcnt(0)+collective barrier at
// tile end; A buffers alternate; vmcnt FIFO: prologue A(0)=4, +B 2 +A' 4
// =10 -> vmcnt(4) drains exactly the 6 oldest; tail uses vmcnt(0).

typedef int i32x4 __attribute__((ext_vector_type(4)));
typedef int i32x8 __attribute__((ext_vector_type(8)));
typedef float f32x4 __attribute__((ext_vector_type(4)));

static constexpr int Bsz = 16384;
static constexpr int Din = 1024;
static constexpr int Hid = 2048;

__device__ __forceinline__ void ld16(const void* g, void* l) {
  __builtin_amdgcn_global_load_lds(
      (const __attribute__((address_space(1))) void*)g,
      (__attribute__((address_space(3))) void*)l, 16, 0, 0);
}

// ---------------- fused prep: sign-quantize to packed fp4 + BN folds -------
// Each thread packs 8 floats -> 8 fp4 nibbles (u32). Elem j -> bits[4j+3:4j].
// blocks [0,8192): x (thr 0.5)   [8192,9216): w1   [9216,11264): w2
// [11264,13312): w3              [13312,13336): bnprep
__global__ void prep_kernel(
    const float* __restrict__ x, const float* __restrict__ w1,
    const float* __restrict__ w2, const float* __restrict__ w3,
    const float* __restrict__ g1, const float* __restrict__ b1,
    const float* __restrict__ m1, const float* __restrict__ v1,
    const float* __restrict__ g2, const float* __restrict__ b2,
    const float* __restrict__ m2, const float* __restrict__ v2,
    const float* __restrict__ g3, const float* __restrict__ b3,
    const float* __restrict__ m3, const float* __restrict__ v3,
    unsigned* __restrict__ A0, unsigned* __restrict__ W1s,
    unsigned* __restrict__ W2s, unsigned* __restrict__ W3s,
    float* __restrict__ a1, float* __restrict__ be1,
    float* __restrict__ a2, float* __restrict__ be2,
    float* __restrict__ a3, float* __restrict__ be3) {
  constexpr int BX = 8192, BW1 = 1024, BW2 = 2048, BW3 = 2048;
  const int blk = blockIdx.x;
  if (blk < BX + BW1 + BW2 + BW3) {
    const float* s;
    unsigned* d;
    float thr = 0.0f;
    int rb;
    if (blk < BX) {
      s = x; d = A0; thr = 0.5f; rb = 0;
    } else if (blk < BX + BW1) {
      s = w1; d = W1s; rb = BX;
    } else if (blk < BX + BW1 + BW2) {
      s = w2; d = W2s; rb = BX + BW1;
    } else {
      s = w3; d = W3s; rb = BX + BW1 + BW2;
    }
    int i = (blk - rb) * 256 + threadIdx.x;
    float4 v0 = ((const float4*)s)[2 * i];
    float4 v1 = ((const float4*)s)[2 * i + 1];
    float e[8] = {v0.x, v0.y, v0.z, v0.w, v1.x, v1.y, v1.z, v1.w};
    unsigned w = 0;
#pragma unroll
    for (int j = 0; j < 8; ++j)
      w |= ((e[j] >= thr) ? 0x2u : 0xAu) << (4 * j);
    d[i] = w;
  } else {
    int t = (blk - (BX + BW1 + BW2 + BW3)) * 256 + threadIdx.x;  // 0..6143
    int l = t >> 11, e = t & 2047;
    const float *g, *b, *m, *v;
    float *al, *be;
    if (l == 0) { g = g1; b = b1; m = m1; v = v1; al = a1; be = be1; }
    else if (l == 1) { g = g2; b = b2; m = m2; v = v2; al = a2; be = be2; }
    else { g = g3; b = b3; m = m3; v = v3; al = a3; be = be3; }
    float a = g[e] / sqrtf(v[e] + 1e-5f);
    al[e] = a;
    be[e] = b[e] - m[e] * a;
  }
}

// ---------------- fp4 MFMA layer: C = A x W^T -----------------------------
// Block 256(m) x 128(n) x K-tile 128B (=256 elems). 8 waves as 4(m) x 2(n);
// wave tile 64x64 = 4x4 mfma 16x16 frags.
// Staging chunks per tile: A = 32 x 1KB (8 rows each), B = 16 x 1KB.
// Wave w stages A-chunks {4w..4w+3} and B-chunks {2w,2w+1}; each ld16 is
// wave-uniform LDS base + lane*16 (linear dest), source pre-swizzled by
// kc = (lane&7)^(row&7) so reads use the verified zero-conflict pattern.
// Loop per tile t: issue B(t); issue A(t+1)->altA; vmcnt(4) [tail: 0];
// barrier; compute; lgkmcnt(0); barrier.
// FINAL: dot with sign(wout) rows, atomicAdd exact-integer partials (f32).
template <int K, bool FINAL>
__global__ __launch_bounds__(512, 4) void layer_mfma(
    const char* __restrict__ A, const char* __restrict__ W,
    const float* __restrict__ alpha, const float* __restrict__ beta,
    char* __restrict__ O, const float* __restrict__ wout,
    float* __restrict__ out) {
  constexpr int N = Hid;
  constexpr int KB = K / 2;    // bytes per packed row
  constexpr int NT = KB / 128; // K-tiles of 128B (=256 elems)
  __shared__ __align__(16) char lds[81920];  // A dbuf 2x32KB | B 16KB

  const int tid = threadIdx.x;
  const int wave = tid >> 6, lane = tid & 63;

  // R11 swizzle: XCD x (= id&7) owns mp [x*8, x*8+8), np outermost.
  const int id = blockIdx.x;
  const int mp = (id & 7) * 8 + ((id >> 3) & 7);
  const int np = id >> 6;
  const int m0 = mp * 256, n0 = np * 128;

  // ---- staging pointers ----
  // A: 4 chunks/wave (rows c*8 + lane>>3 of the 256-row panel).
  const char* gpA[4];
  int loA[4];  // offset within one A buffer
#pragma unroll
  for (int i = 0; i < 4; ++i) {
    int c = wave * 4 + i;
    int row = c * 8 + (lane >> 3);
    int kc = (lane & 7) ^ (row & 7);
    gpA[i] = A + (size_t)(m0 + row) * KB + kc * 16;
    loA[i] = c * 1024;
  }
  // B: 2 chunks/wave (rows of the 128-row panel), fixed dest @65536.
  const char* gpB[2];
  char* lpB[2];
#pragma unroll
  for (int i = 0; i < 2; ++i) {
    int c = wave * 2 + i;
    int row = c * 8 + (lane >> 3);
    int kc = (lane & 7) ^ (row & 7);
    gpB[i] = W + (size_t)(n0 + row) * KB + kc * 16;
    lpB[i] = &lds[65536 + c * 1024];
  }

  // ---- fragment reads: R11's verified zero-conflict pattern ----
  const int lr = lane & 15, lk = lane >> 4;
  const int wm = wave >> 1, wn = wave & 1;
  const int xs0 = ((0 + lk) ^ (lr & 7)) * 16;  // k-slice 0 chunk slot
  const int xs1 = ((4 + lk) ^ (lr & 7)) * 16;  // k-slice 1 chunk slot
  const int aofs = (wm * 64 + lr) * 128;              // + abuf + mt*2048 + xs
  const int bbase = 65536 + (wn * 64 + lr) * 128;     // + nt*2048 + xs

  f32x4 acc[4][4] = {};
  i32x8 aop = {};      // fp4 uses low 4 regs; high half stays zero
  i32x8 bop[4] = {};

  // prologue: issue A(0) into buf0 (drained by tile-0's vmcnt).
#pragma unroll
  for (int i = 0; i < 4; ++i) {
    ld16(gpA[i], lds + loA[i]);
    gpA[i] += 128;
  }

#pragma unroll 1
  for (int t = 0; t < NT; ++t) {
    const int abuf = (t & 1) << 15;   // A read buffer
    const int altA = abuf ^ 32768;    // A prefetch buffer
    // B(t) into the single B buffer (prev readers passed last barrier).
#pragma unroll
    for (int i = 0; i < 2; ++i) {
      ld16(gpB[i], lpB[i]);
      gpB[i] += 128;
    }
    if (t + 1 < NT) {
      // A(t+1) into the alternate buffer -- a full tile to land.
#pragma unroll
      for (int i = 0; i < 4; ++i) {
        ld16(gpA[i], lds + altA + loA[i]);
        gpA[i] += 128;
      }
      // drain A(t)+B(t) (6 oldest), keep A(t+1)'s 4 in flight.
      asm volatile("s_waitcnt vmcnt(4)" ::: "memory");
    } else {
      asm volatile("s_waitcnt vmcnt(0)" ::: "memory");
    }
    __builtin_amdgcn_s_barrier();  // all waves' A(t),B(t) resident

#pragma unroll
    for (int s = 0; s < 2; ++s) {
      const int xs = s ? xs1 : xs0;
#pragma unroll
      for (int nt = 0; nt < 4; ++nt)
        *(i32x4*)&bop[nt] = *(const i32x4*)(lds + bbase + nt * 2048 + xs);
#pragma unroll
      for (int mt = 0; mt < 4; ++mt) {
        *(i32x4*)&aop = *(const i32x4*)(lds + abuf + aofs + mt * 2048 + xs);
#pragma unroll
        for (int nt = 0; nt < 4; ++nt)
          acc[mt][nt] = __builtin_amdgcn_mfma_scale_f32_16x16x128_f8f6f4(
              aop, bop[nt], acc[mt][nt], 4, 4,   // FMT A=fp4, B=fp4
              0, 0x7F7F7F7F, 0, 0x7F7F7F7F);     // scales = 1.0 (E8M0 127)
      }
    }
    // all own ds_reads retired (MFMA consumed them); collective barrier
    // publishes: B buffer free for B(t+1), altA free after its tile.
    asm volatile("s_waitcnt lgkmcnt(0)" ::: "memory");
    __builtin_amdgcn_s_barrier();
  }

  float al[4], be[4];
#pragma unroll
  for (int nt = 0; nt < 4; ++nt) {
    int n = n0 + wn * 64 + nt * 16 + lr;
    al[nt] = alpha[n];
    be[nt] = beta[n];
  }

  if (!FINAL) {
    // pack output fp4 nibbles: lane pairs share one byte; even lane stores.
    const int bb0 = (n0 + wn * 64) >> 1;
#pragma unroll
    for (int mt = 0; mt < 4; ++mt)
#pragma unroll
      for (int r = 0; r < 4; ++r) {
        int m = m0 + wm * 64 + mt * 16 + lk * 4 + r;  // C/D row=(lane>>4)*4+reg
        char* orow = O + (size_t)m * (N / 2);
#pragma unroll
        for (int nt = 0; nt < 4; ++nt) {
          unsigned nib =
              (fmaf(al[nt], acc[mt][nt][r], be[nt]) >= 0.0f) ? 0x2u : 0xAu;
          unsigned pn = __shfl_xor(nib, 1, 64);
          if ((lane & 1) == 0)
            orow[bb0 + ((nt * 16 + lr) >> 1)] = (char)(nib | (pn << 4));
        }
      }
  } else {
    int ws0[4], ws1[4];
#pragma unroll
    for (int nt = 0; nt < 4; ++nt) {
      int n = n0 + wn * 64 + nt * 16 + lr;
      ws0[nt] = (wout[n] >= 0.0f) ? 1 : -1;
      ws1[nt] = (wout[2048 + n] >= 0.0f) ? 1 : -1;
    }
#pragma unroll
    for (int mt = 0; mt < 4; ++mt)
#pragma unroll
      for (int r = 0; r < 4; ++r) {
        int m = m0 + wm * 64 + mt * 16 + lk * 4 + r;
        int p0 = 0, p1 = 0;
#pragma unroll
        for (int nt = 0; nt < 4; ++nt) {
          int a = (fmaf(al[nt], acc[mt][nt][r], be[nt]) >= 0.0f) ? 1 : -1;
          p0 += a * ws0[nt];
          p1 += a * ws1[nt];
        }
        // reduce across lr (lane bits 0..3)
#pragma unroll
        for (int off = 1; off <= 8; off <<= 1) {
          p0 += __shfl_xor(p0, off, 64);
          p1 += __shfl_xor(p1, off, 64);
        }
        if (lr == 0) {
          atomicAdd(&out[m * 2 + 0], (float)p0);
          atomicAdd(&out[m * 2 + 1], (float)p1);
        }
      }
  }
}

extern "C" void kernel_launch(void* const* d_in, const int* in_sizes, int n_in,
                              void* d_out, int out_size, void* d_ws, size_t ws_size,
                              hipStream_t stream) {
  const float* x    = (const float*)d_in[0];
  const float* w1   = (const float*)d_in[1];
  const float* g1   = (const float*)d_in[2];
  const float* b1   = (const float*)d_in[3];
  const float* m1   = (const float*)d_in[4];
  const float* v1   = (const float*)d_in[5];
  const float* w2   = (const float*)d_in[6];
  const float* g2   = (const float*)d_in[7];
  const float* b2   = (const float*)d_in[8];
  const float* m2   = (const float*)d_in[9];
  const float* v2   = (const float*)d_in[10];
  const float* w3   = (const float*)d_in[11];
  const float* g3   = (const float*)d_in[12];
  const float* b3   = (const float*)d_in[13];
  const float* m3   = (const float*)d_in[14];
  const float* v3   = (const float*)d_in[15];
  const float* wout = (const float*)d_in[16];
  float* out = (float*)d_out;

  char* base = (char*)d_ws;
  size_t off = 0;
  auto take = [&](size_t bytes) -> char* {
    char* p = base + off;
    off += (bytes + 255) & ~(size_t)255;
    return p;
  };
  char* A0  = take((size_t)Bsz * Din / 2);
  char* Aa  = take((size_t)Bsz * Hid / 2);
  char* Ab  = take((size_t)Bsz * Hid / 2);
  char* W1s = take((size_t)Hid * Din / 2);
  char* W2s = take((size_t)Hid * Hid / 2);
  char* W3s = take((size_t)Hid * Hid / 2);
  float* a1  = (float*)take(Hid * 4);
  float* be1 = (float*)take(Hid * 4);
  float* a2  = (float*)take(Hid * 4);
  float* be2 = (float*)take(Hid * 4);
  float* a3  = (float*)take(Hid * 4);
  float* be3 = (float*)take(Hid * 4);

  hipMemsetAsync(d_out, 0, (size_t)out_size * sizeof(float), stream);

  prep_kernel<<<13336, 256, 0, stream>>>(
      x, w1, w2, w3,
      g1, b1, m1, v1, g2, b2, m2, v2, g3, b3, m3, v3,
      (unsigned*)A0, (unsigned*)W1s, (unsigned*)W2s, (unsigned*)W3s,
      a1, be1, a2, be2, a3, be3);

  // grid 1024: (16384/256) m-panels x (2048/128) n-panels, XCD-swizzled
  layer_mfma<Din, false><<<1024, 512, 0, stream>>>(A0, W1s, a1, be1, Aa,
                                                   nullptr, nullptr);
  layer_mfma<Hid, false><<<1024, 512, 0, stream>>>(Aa, W2s, a2, be2, Ab,
                                                   nullptr, nullptr);
  layer_mfma<Hid, true><<<1024, 512, 0, stream>>>(Ab, W3s, a3, be3, nullptr,
                                                  wout, out);
}